// Round 6
// baseline (182.991 us; speedup 1.0000x reference)
//
#include <hip/hip_runtime.h>
#include <math.h>
#include <float.h>

// Problem constants (fixed by the reference)
#define Bn   64
#define Sn   512
#define En   128
#define Hn   128
#define G4   512     // 4*H
#define FWn  6
#define Wn   507     // S - FW + 1
#define WT   64      // windows per block (M = 4 m-tiles)
#define NTILE 8      // 507 windows -> 8 tiles of 64

#define XROWS   69    // rows of x staged per block (64 windows + FW-1)
#define XSTRIDE 136   // fp16 elems per x row (272 B pad; phase-wise conflict-free)

typedef __attribute__((ext_vector_type(8))) _Float16 half8;
typedef __attribute__((ext_vector_type(4))) float f32x4;

// Fast activations: v_exp_f32 + v_rcp_f32 (1 ulp), NaN-free at extremes.
__device__ __forceinline__ float sigf(float x)  {
    return __builtin_amdgcn_rcpf(1.0f + __expf(-x));
}
__device__ __forceinline__ float tanh_(float x) {
    return 1.0f - 2.0f * __builtin_amdgcn_rcpf(__expf(2.0f * x) + 1.0f);
}

// ---------------------------------------------------------------------------
// Kernel 0: pack w_ih and w_hh (both [512][128] f32) into fp16 B-fragment
// order for mfma_f32_16x16x32_f16:
//   pack[((nt*4 + ks)*64 + lane)*8 + j] = w[nt*16 + (lane&15)][ks*32 + (lane>>4)*8 + j]
// Row-tile nt = g*8 + ut (gate g, unit-tile ut). 65536 elements each.
// ---------------------------------------------------------------------------
__global__ void __launch_bounds__(256)
pack_w_kernel(const float* __restrict__ w_ih, const float* __restrict__ w_hh,
              _Float16* __restrict__ wih_p, _Float16* __restrict__ whh_p)
{
    const int idx = blockIdx.x * 256 + threadIdx.x;      // 0..65535
    const int j  = idx & 7;
    const int L  = (idx >> 3) & 63;
    const int ks = (idx >> 9) & 3;
    const int nt = idx >> 11;
    const int row = nt * 16 + (L & 15);
    const int col = ks * 32 + (L >> 4) * 8 + j;
    wih_p[idx] = (_Float16)w_ih[row * 128 + col];
    whh_p[idx] = (_Float16)w_hh[row * 128 + col];
}

// ---------------------------------------------------------------------------
// Kernel 1 (fused MFMA LSTM), M=64: 64 windows per block, 6 steps.
//   - B-fragments (wih/whh, L2-resident) reused across 4 m-tiles -> weight
//     L2 traffic halves vs M=32 (the R5 limiter: 1.44 GB -> 0.70 GB).
//   - x rows staged once in LDS fp16; h double-buffered in LDS A-frag order,
//     1 barrier/step; h written per-uti immediately (incl. step 5) so no
//     persistent hcur registers; window-max re-reads h from LDS.
//   NOTE: no min-waves launch bound — R3 showed a forced VGPR cap causes
//   catastrophic scratch spill.
// grid 64*8, block 256.
// ---------------------------------------------------------------------------
__global__ void __launch_bounds__(256)
lstm_kernel(const int* __restrict__ inputs, const float* __restrict__ embed,
            const _Float16* __restrict__ wih_p, const _Float16* __restrict__ whh_p,
            const float* __restrict__ b_ih, const float* __restrict__ b_hh,
            float* __restrict__ partial)
{
    __shared__ __align__(16) _Float16 x_win[XROWS * XSTRIDE];  // 18.3 KB
    __shared__ __align__(16) _Float16 hsA[2][8192];            // 2 x 16 KB
    const int t    = threadIdx.x;
    const int L    = t & 63;
    const int wv   = t >> 6;
    const int b    = blockIdx.x >> 3;
    const int tile = blockIdx.x & 7;
    const int w0   = tile * WT;
    const int q  = L >> 4;
    const int ln = L & 15;
    const int j8 = L & 7;

    // ---- stage x rows (gather embed, cvt fp16) ----
    {
        const int rr = t >> 3;          // 0..31
        const int lc = t & 7;           // 16-float chunk within row
#pragma unroll
        for (int base = 0; base < XROWS + 31; base += 32) {
            const int i = base + rr;
            if (i < XROWS) {
                int s = w0 + i; s = s < 511 ? s : 511;   // clamp (masked at max)
                const int tok = inputs[b * Sn + s];
                const float* er = embed + (size_t)tok * 128 + lc * 16;
                float4 e0 = *(const float4*)(er);
                float4 e1 = *(const float4*)(er + 4);
                float4 e2 = *(const float4*)(er + 8);
                float4 e3 = *(const float4*)(er + 12);
                half8 h0, h1;
                h0[0] = (_Float16)e0.x; h0[1] = (_Float16)e0.y;
                h0[2] = (_Float16)e0.z; h0[3] = (_Float16)e0.w;
                h0[4] = (_Float16)e1.x; h0[5] = (_Float16)e1.y;
                h0[6] = (_Float16)e1.z; h0[7] = (_Float16)e1.w;
                h1[0] = (_Float16)e2.x; h1[1] = (_Float16)e2.y;
                h1[2] = (_Float16)e2.z; h1[3] = (_Float16)e2.w;
                h1[4] = (_Float16)e3.x; h1[5] = (_Float16)e3.y;
                h1[6] = (_Float16)e3.z; h1[7] = (_Float16)e3.w;
                *(half8*)&x_win[i * XSTRIDE + lc * 16]     = h0;
                *(half8*)&x_win[i * XSTRIDE + lc * 16 + 8] = h1;
            }
        }
    }

    // per-lane gate biases for this wave's 2 unit-tiles
    float biasg[2][4];
#pragma unroll
    for (int uti = 0; uti < 2; ++uti) {
        const int u = (wv * 2 + uti) * 16 + ln;
#pragma unroll
        for (int g = 0; g < 4; ++g)
            biasg[uti][g] = b_ih[g * 128 + u] + b_hh[g * 128 + u];
    }

    float cst[2][4][4];    // [uti][mt][r] cell state (persistent)
#pragma unroll
    for (int uti = 0; uti < 2; ++uti)
#pragma unroll
        for (int mt = 0; mt < 4; ++mt)
#pragma unroll
            for (int r = 0; r < 4; ++r) cst[uti][mt][r] = 0.0f;

    __syncthreads();       // x_win staged

    // ---- steps 0..5 ----
    for (int st = 0; st < FWn; ++st) {
        if (st > 0) __syncthreads();            // prev step's h writes visible
        const _Float16* hb  = hsA[(st + 1) & 1]; // h(st-1), written at end of st-1
        _Float16*       buf = hsA[st & 1];       // h(st) destination

#pragma unroll
        for (int uti = 0; uti < 2; ++uti) {
            const int ut = wv * 2 + uti;
            f32x4 acc[4][4];                // [mt][gate]
#pragma unroll
            for (int mt = 0; mt < 4; ++mt)
#pragma unroll
                for (int g = 0; g < 4; ++g) {
                    const float bg = biasg[uti][g];
                    acc[mt][g] = (f32x4){bg, bg, bg, bg};
                }
            // input projection: x rows st + mt*16 + ln
#pragma unroll
            for (int ks = 0; ks < 4; ++ks) {
                half8 ax[4];
#pragma unroll
                for (int mt = 0; mt < 4; ++mt)
                    ax[mt] = *(const half8*)&x_win[(st + mt * 16 + ln) * XSTRIDE + ks * 32 + q * 8];
#pragma unroll
                for (int g = 0; g < 4; ++g) {
                    const int nt = g * 8 + ut;
                    half8 bw = *(const half8*)(wih_p + ((size_t)(nt * 4 + ks) * 64 + L) * 8);
#pragma unroll
                    for (int mt = 0; mt < 4; ++mt)
                        acc[mt][g] = __builtin_amdgcn_mfma_f32_16x16x32_f16(ax[mt], bw, acc[mt][g], 0, 0, 0);
                }
            }
            // hidden projection (skip at st=0: h=0)
            if (st > 0) {
#pragma unroll
                for (int ks = 0; ks < 4; ++ks) {
                    half8 ah[4];
#pragma unroll
                    for (int mt = 0; mt < 4; ++mt)
                        ah[mt] = *(const half8*)(hb + ((mt * 4 + ks) * 64 + L) * 8);
#pragma unroll
                    for (int g = 0; g < 4; ++g) {
                        const int nt = g * 8 + ut;
                        half8 bh = *(const half8*)(whh_p + ((size_t)(nt * 4 + ks) * 64 + L) * 8);
#pragma unroll
                        for (int mt = 0; mt < 4; ++mt)
                            acc[mt][g] = __builtin_amdgcn_mfma_f32_16x16x32_f16(ah[mt], bh, acc[mt][g], 0, 0, 0);
                    }
                }
            }
            // gate nonlinearity + state update + immediate h scatter to LDS
            {
                const int ks  = ut >> 1;
                const int lamb = 16 * ((ut & 1) * 2 + (ln >> 3));
#pragma unroll
                for (int mt = 0; mt < 4; ++mt)
#pragma unroll
                    for (int r = 0; r < 4; ++r) {
                        float ii = sigf(acc[mt][0][r]);
                        float ff = sigf(acc[mt][1][r]);
                        float gg = tanh_(acc[mt][2][r]);
                        float oo = sigf(acc[mt][3][r]);
                        float cc = ff * cst[uti][mt][r] + ii * gg;
                        cst[uti][mt][r] = cc;
                        float hh = oo * tanh_(cc);
                        buf[((mt * 4 + ks) * 64 + (q * 4 + r + lamb)) * 8 + j8] = (_Float16)hh;
                    }
            }
        }
    }

    // ---- max over windows from LDS h(st=5) (mask invalid), reduce across q ----
    __syncthreads();
    const _Float16* hf = hsA[(FWn - 1) & 1];   // hsA[1]
#pragma unroll
    for (int uti = 0; uti < 2; ++uti) {
        const int ut   = wv * 2 + uti;
        const int ks   = ut >> 1;
        const int lamb = 16 * ((ut & 1) * 2 + (ln >> 3));
        float mv = -FLT_MAX;
#pragma unroll
        for (int mt = 0; mt < 4; ++mt)
#pragma unroll
            for (int r = 0; r < 4; ++r) {
                const int w = w0 + mt * 16 + q * 4 + r;
                float hv = (float)hf[((mt * 4 + ks) * 64 + (q * 4 + r + lamb)) * 8 + j8];
                if (w < Wn) mv = fmaxf(mv, hv);
            }
        mv = fmaxf(mv, __shfl_xor(mv, 16));
        mv = fmaxf(mv, __shfl_xor(mv, 32));
        if (q == 0)
            partial[(size_t)(b * NTILE + tile) * 128 + ut * 16 + ln] = mv;
    }
}

// ---------------------------------------------------------------------------
// Kernel 2: feat[b][u] = max over tiles; out[b][c] = feat . fc_w[c] + fc_b[c]
// grid 64, block 128
// ---------------------------------------------------------------------------
__global__ void __launch_bounds__(128)
final_kernel(const float* __restrict__ partial, const float* __restrict__ fc_w,
             const float* __restrict__ fc_b, float* __restrict__ out)
{
    const int b = blockIdx.x;
    const int u = threadIdx.x;
    float m = -FLT_MAX;
#pragma unroll
    for (int tl = 0; tl < NTILE; ++tl)
        m = fmaxf(m, partial[(size_t)(b * NTILE + tl) * 128 + u]);
    float v0 = m * fc_w[u];
    float v1 = m * fc_w[128 + u];
#pragma unroll
    for (int off = 1; off < 64; off <<= 1) {
        v0 += __shfl_xor(v0, off);
        v1 += __shfl_xor(v1, off);
    }
    __shared__ float red[2][2];
    if ((u & 63) == 0) { red[u >> 6][0] = v0; red[u >> 6][1] = v1; }
    __syncthreads();
    if (u == 0) {
        out[b * 2 + 0] = red[0][0] + red[1][0] + fc_b[0];
        out[b * 2 + 1] = red[0][1] + red[1][1] + fc_b[1];
    }
}

// ---------------------------------------------------------------------------
extern "C" void kernel_launch(void* const* d_in, const int* in_sizes, int n_in,
                              void* d_out, int out_size, void* d_ws, size_t ws_size,
                              hipStream_t stream)
{
    const int*   inputs = (const int*)d_in[0];
    // d_in[1] = lengths : unused by the reference
    const float* embed  = (const float*)d_in[2];
    const float* w_ih   = (const float*)d_in[3];
    const float* w_hh   = (const float*)d_in[4];
    const float* b_ih   = (const float*)d_in[5];
    const float* b_hh   = (const float*)d_in[6];
    const float* fc_w   = (const float*)d_in[7];
    const float* fc_b   = (const float*)d_in[8];
    float* out = (float*)d_out;

    // workspace: partial (256 KiB) | wih_p, whh_p (128 KiB each)
    float*    partial = (float*)d_ws;
    _Float16* wih_p   = (_Float16*)(partial + Bn * NTILE * 128);
    _Float16* whh_p   = wih_p + 65536;

    pack_w_kernel<<<dim3(256), 256, 0, stream>>>(w_ih, w_hh, wih_p, whh_p);
    lstm_kernel<<<dim3(Bn * NTILE), 256, 0, stream>>>(inputs, embed, wih_p, whh_p,
                                                      b_ih, b_hh, partial);
    final_kernel<<<dim3(Bn), 128, 0, stream>>>(partial, fc_w, fc_b, out);
}

// Round 7
// 146.552 us; speedup vs baseline: 1.2486x; 1.2486x over previous
//
#include <hip/hip_runtime.h>
#include <math.h>
#include <float.h>

// Problem constants (fixed by the reference)
#define Bn   64
#define Sn   512
#define FWn  6
#define Wn   507     // S - FW + 1
#define WT   16      // windows per block
#define NTILE 32     // 507 windows -> 32 tiles of 16

#define PROWS   21    // projection rows per block (16 windows + FW-1)
#define PSTRIDE 516   // f32 elems per Pt row (+4 pad)

typedef __attribute__((ext_vector_type(8))) _Float16 half8;
typedef __attribute__((ext_vector_type(4))) float f32x4;

// Fast activations: v_exp_f32 + v_rcp_f32 (1 ulp), NaN-free at extremes.
__device__ __forceinline__ float sigf(float x)  {
    return __builtin_amdgcn_rcpf(1.0f + __expf(-x));
}
__device__ __forceinline__ float tanh_(float x) {
    return 1.0f - 2.0f * __builtin_amdgcn_rcpf(__expf(2.0f * x) + 1.0f);
}

// ---------------------------------------------------------------------------
// Kernel 0: pack w_ih and w_hh (both [512][128] f32) into fp16 B-fragment
// order for mfma_f32_16x16x32_f16:
//   pack[((nt*4 + ks)*64 + lane)*8 + j] = w[nt*16 + (lane&15)][ks*32 + (lane>>4)*8 + j]
// Row-tile nt = g*8 + ut (gate g, unit-tile ut). 65536 elements each.
// ---------------------------------------------------------------------------
__global__ void __launch_bounds__(256)
pack_w_kernel(const float* __restrict__ w_ih, const float* __restrict__ w_hh,
              _Float16* __restrict__ wih_p, _Float16* __restrict__ whh_p)
{
    const int idx = blockIdx.x * 256 + threadIdx.x;      // 0..65535
    const int j  = idx & 7;
    const int L  = (idx >> 3) & 63;
    const int ks = (idx >> 9) & 3;
    const int nt = idx >> 11;
    const int row = nt * 16 + (L & 15);
    const int col = ks * 32 + (L >> 4) * 8 + j;
    wih_p[idx] = (_Float16)w_ih[row * 128 + col];
    whh_p[idx] = (_Float16)w_hh[row * 128 + col];
}

// ---------------------------------------------------------------------------
// Kernel 1 (fused MFMA LSTM), 16 windows/block, 512 threads (8 waves).
//   Wave wv owns unit-tile ut = wv (16 hidden units).
//   Phase 1: x-projection for rows [w0, w0+20] computed ONCE via MFMA into
//     LDS Pt[21][512] fp32 (+bias, gate-interleaved float4 per (row,unit)).
//     w_hh B-fragments (16 x half8 = 64 VGPR) register-resident per wave.
//   Phase 2: 6 steps; acc init = 4 float4 Pt reads (full fp32 projection);
//     h-proj = 16 MFMA from register whh; h exchanged via 8 KB double-
//     buffered A-fragment LDS, 1 barrier/step.
//   Weight L2 traffic: one-time 256 KB/block (vs per-step re-stream in R5/R6).
//   NOTE: no min-waves launch bound — R3 showed a forced VGPR cap causes
//   catastrophic scratch spill.
// grid 64*32, block 512.
// ---------------------------------------------------------------------------
__global__ void __launch_bounds__(512)
lstm_kernel(const int* __restrict__ inputs, const float* __restrict__ embed,
            const _Float16* __restrict__ wih_p, const _Float16* __restrict__ whh_p,
            const float* __restrict__ b_ih, const float* __restrict__ b_hh,
            float* __restrict__ partial)
{
    __shared__ __align__(16) float    Pt[PROWS * PSTRIDE];  // 43.3 KB
    __shared__ __align__(16) _Float16 hsA[2][2048];         // 2 x 4 KB
    const int t    = threadIdx.x;
    const int L    = t & 63;
    const int ut   = t >> 6;          // wave index = unit-tile 0..7
    const int b    = blockIdx.x >> 5;
    const int tile = blockIdx.x & 31;
    const int w0   = tile * WT;
    const int q  = L >> 4;
    const int ln = L & 15;
    const int j8 = L & 7;
    const int u  = ut * 16 + ln;      // this lane's hidden unit (B n-index)

    // ---- phase 1: x-proj (2 m-tiles = rows 0..31, stores clamped to 21) ----
    {
        f32x4 accx[2][4];   // [mt][gate], init with bias
#pragma unroll
        for (int g = 0; g < 4; ++g) {
            const float bg = b_ih[g * 128 + u] + b_hh[g * 128 + u];
            accx[0][g] = (f32x4){bg, bg, bg, bg};
            accx[1][g] = accx[0][g];
        }
        int tok[2];
#pragma unroll
        for (int mt = 0; mt < 2; ++mt) {
            int s = w0 + mt * 16 + ln; s = s < 511 ? s : 511;  // clamp (masked at max)
            tok[mt] = inputs[b * Sn + s];
        }
#pragma unroll
        for (int ks = 0; ks < 4; ++ks) {
            half8 ax[2];
#pragma unroll
            for (int mt = 0; mt < 2; ++mt) {
                const float* er = embed + (size_t)tok[mt] * 128 + ks * 32 + q * 8;
                float4 e0 = *(const float4*)er;
                float4 e1 = *(const float4*)(er + 4);
                half8 a;
                a[0] = (_Float16)e0.x; a[1] = (_Float16)e0.y;
                a[2] = (_Float16)e0.z; a[3] = (_Float16)e0.w;
                a[4] = (_Float16)e1.x; a[5] = (_Float16)e1.y;
                a[6] = (_Float16)e1.z; a[7] = (_Float16)e1.w;
                ax[mt] = a;
            }
#pragma unroll
            for (int g = 0; g < 4; ++g) {
                half8 bw = *(const half8*)(wih_p + ((size_t)((g * 8 + ut) * 4 + ks) * 64 + L) * 8);
                accx[0][g] = __builtin_amdgcn_mfma_f32_16x16x32_f16(ax[0], bw, accx[0][g], 0, 0, 0);
                accx[1][g] = __builtin_amdgcn_mfma_f32_16x16x32_f16(ax[1], bw, accx[1][g], 0, 0, 0);
            }
        }
        // store gate-interleaved Pt rows (predicated to 21 rows)
#pragma unroll
        for (int mt = 0; mt < 2; ++mt)
#pragma unroll
            for (int r = 0; r < 4; ++r) {
                const int sl = mt * 16 + q * 4 + r;
                if (sl < PROWS) {
                    float4 o = {accx[mt][0][r], accx[mt][1][r],
                                accx[mt][2][r], accx[mt][3][r]};
                    *(float4*)&Pt[sl * PSTRIDE + u * 4] = o;
                }
            }
    }

    // register-resident w_hh B-fragments for this wave's unit-tile
    half8 whf[4][4];    // [gate][ks]
#pragma unroll
    for (int g = 0; g < 4; ++g)
#pragma unroll
        for (int ks = 0; ks < 4; ++ks)
            whf[g][ks] = *(const half8*)(whh_p + ((size_t)((g * 8 + ut) * 4 + ks) * 64 + L) * 8);

    __syncthreads();    // Pt visible to all waves

    // h scatter address components (A-fragment layout for unit u, window m)
    const int ks_h = ut >> 1;
    const int qp   = (ut & 1) * 2 + (ln >> 3);

    float cst[4] = {0.f, 0.f, 0.f, 0.f};
    float hh[4];

    // ---- steps 0..5 ----
    for (int st = 0; st < FWn; ++st) {
        if (st > 0) __syncthreads();        // prev step's h scatter visible
        f32x4 acc[4];                       // [gate] over r
#pragma unroll
        for (int r = 0; r < 4; ++r) {
            float4 pv = *(const float4*)&Pt[(q * 4 + r + st) * PSTRIDE + u * 4];
            acc[0][r] = pv.x; acc[1][r] = pv.y;
            acc[2][r] = pv.z; acc[3][r] = pv.w;
        }
        if (st > 0) {
            const _Float16* hb = hsA[(st + 1) & 1];   // h(st-1)
#pragma unroll
            for (int ks = 0; ks < 4; ++ks) {
                half8 ah = *(const half8*)(hb + (ks * 64 + L) * 8);
#pragma unroll
                for (int g = 0; g < 4; ++g)
                    acc[g] = __builtin_amdgcn_mfma_f32_16x16x32_f16(ah, whf[g][ks], acc[g], 0, 0, 0);
            }
        }
        _Float16* buf = hsA[st & 1];
#pragma unroll
        for (int r = 0; r < 4; ++r) {
            float ii = sigf(acc[0][r]);
            float ff = sigf(acc[1][r]);
            float gg = tanh_(acc[2][r]);
            float oo = sigf(acc[3][r]);
            float cc = ff * cst[r] + ii * gg;
            cst[r] = cc;
            hh[r] = oo * tanh_(cc);
            if (st < FWn - 1)
                buf[ks_h * 512 + (qp * 16 + q * 4 + r) * 8 + j8] = (_Float16)hh[r];
        }
    }

    // ---- max over this block's 16 windows (mask invalid), reduce across q ----
    float mv = -FLT_MAX;
#pragma unroll
    for (int r = 0; r < 4; ++r) {
        const int w = w0 + q * 4 + r;
        if (w < Wn) mv = fmaxf(mv, hh[r]);
    }
    mv = fmaxf(mv, __shfl_xor(mv, 16));
    mv = fmaxf(mv, __shfl_xor(mv, 32));
    if (q == 0)
        partial[(size_t)(b * NTILE + tile) * 128 + u] = mv;
}

// ---------------------------------------------------------------------------
// Kernel 2: feat[b][u] = max over tiles; out[b][c] = feat . fc_w[c] + fc_b[c]
// grid 64, block 128
// ---------------------------------------------------------------------------
__global__ void __launch_bounds__(128)
final_kernel(const float* __restrict__ partial, const float* __restrict__ fc_w,
             const float* __restrict__ fc_b, float* __restrict__ out)
{
    const int b = blockIdx.x;
    const int u = threadIdx.x;
    float m = -FLT_MAX;
#pragma unroll
    for (int tl = 0; tl < NTILE; ++tl)
        m = fmaxf(m, partial[(size_t)(b * NTILE + tl) * 128 + u]);
    float v0 = m * fc_w[u];
    float v1 = m * fc_w[128 + u];
#pragma unroll
    for (int off = 1; off < 64; off <<= 1) {
        v0 += __shfl_xor(v0, off);
        v1 += __shfl_xor(v1, off);
    }
    __shared__ float red[2][2];
    if ((u & 63) == 0) { red[u >> 6][0] = v0; red[u >> 6][1] = v1; }
    __syncthreads();
    if (u == 0) {
        out[b * 2 + 0] = red[0][0] + red[1][0] + fc_b[0];
        out[b * 2 + 1] = red[0][1] + red[1][1] + fc_b[1];
    }
}

// ---------------------------------------------------------------------------
extern "C" void kernel_launch(void* const* d_in, const int* in_sizes, int n_in,
                              void* d_out, int out_size, void* d_ws, size_t ws_size,
                              hipStream_t stream)
{
    const int*   inputs = (const int*)d_in[0];
    // d_in[1] = lengths : unused by the reference
    const float* embed  = (const float*)d_in[2];
    const float* w_ih   = (const float*)d_in[3];
    const float* w_hh   = (const float*)d_in[4];
    const float* b_ih   = (const float*)d_in[5];
    const float* b_hh   = (const float*)d_in[6];
    const float* fc_w   = (const float*)d_in[7];
    const float* fc_b   = (const float*)d_in[8];
    float* out = (float*)d_out;

    // workspace: partial (1 MiB) | wih_p, whh_p (128 KiB each)
    float*    partial = (float*)d_ws;
    _Float16* wih_p   = (_Float16*)(partial + Bn * NTILE * 128);
    _Float16* whh_p   = wih_p + 65536;

    pack_w_kernel<<<dim3(256), 256, 0, stream>>>(w_ih, w_hh, wih_p, whh_p);
    lstm_kernel<<<dim3(Bn * NTILE), 512, 0, stream>>>(inputs, embed, wih_p, whh_p,
                                                      b_ih, b_hh, partial);
    final_kernel<<<dim3(Bn), 128, 0, stream>>>(partial, fc_w, fc_b, out);
}